// Round 13
// baseline (515.983 us; speedup 1.0000x reference)
//
#include <hip/hip_runtime.h>
#include <hip/hip_bf16.h>
#include <math.h>

#define CDIV(a,b) (((a)+(b)-1)/(b))

typedef __attribute__((ext_vector_type(8))) short short8v;   // 8 bf16
typedef __attribute__((ext_vector_type(4))) float f32x4;

__device__ inline float bf2lo(unsigned u) { return __uint_as_float(u << 16); }
__device__ inline float bf2hi(unsigned u) { return __uint_as_float(u & 0xffff0000u); }
__device__ inline float leaky(float v) { return v > 0.f ? v : 0.2f * v; }

// ---------------- weight transposes + buffer zeroing in one launch ----------------
__global__ void k_prep(const float* __restrict__ W1, __hip_bfloat16* __restrict__ W1t,
                       const float* __restrict__ Wl1, __hip_bfloat16* __restrict__ Wl1t,
                       const float* __restrict__ W2, __hip_bfloat16* __restrict__ W2t,
                       const float* __restrict__ Wl2, __hip_bfloat16* __restrict__ Wl2t,
                       const float* __restrict__ Wc, float* __restrict__ Wct,
                       const float* __restrict__ Wq, float* __restrict__ Wqt,
                       float* __restrict__ colsum, int* __restrict__ degz,
                       float* __restrict__ esz, int N) {
  int i = blockIdx.x * 256 + threadIdx.x;
  const int n1 = 128 * 512, n2 = 512 * 128, n3 = 128 * 640, n4 = 640 * 128;
  const int n5 = 954 * 128, n6 = 128 * 384;
  if (i < n1) { int m = i / 128, k = i % 128; W1t[i] = __float2bfloat16(W1[(size_t)k * 512 + m]); return; }
  i -= n1;
  if (i < n2) { int m = i / 512, k = i % 512; Wl1t[i] = __float2bfloat16(Wl1[(size_t)k * 128 + m]); return; }
  i -= n2;
  if (i < n3) { int m = i / 128, k = i % 128; W2t[i] = __float2bfloat16(W2[(size_t)k * 640 + m]); return; }
  i -= n3;
  if (i < n4) { int m = i / 640, k = i % 640; Wl2t[i] = __float2bfloat16(Wl2[(size_t)k * 128 + m]); return; }
  i -= n4;
  if (i < n5) { int m = i / 954, k = i % 954; Wct[i] = Wc[(size_t)k * 128 + m]; return; }
  i -= n5;
  if (i < n6) { int m = i / 128, k = i % 128; Wqt[i] = Wq[(size_t)k * 384 + m]; return; }
  i -= n6;
  if (i < 128) { colsum[i] = 0.f; return; }
  i -= 128;
  if (i < 2 * N) { degz[i] = 0; return; }   // degb and cursor contiguous
  i -= 2 * N;
  if (i < 18 * N) { esz[i] = 0.f; return; } // es1(4N) ed1(4N) es2(5N) ed2(5N) contiguous
}

// ---------------- fused: degree count (first E threads) + drug linear (rest) ----------
__global__ void k_degdrug(const int* __restrict__ src0, const int* __restrict__ dst0,
                          int* __restrict__ deg, int E,
                          const int* __restrict__ trip, const float* __restrict__ Wd,
                          const float* __restrict__ bd, __hip_bfloat16* __restrict__ x,
                          int N) {
  int i = blockIdx.x * 256 + threadIdx.x;
  if (i < E) {
    int s = src0[i], d = dst0[i];
    if (s != d) atomicAdd(&deg[d], 1);
    return;
  }
  i -= E;
  if (i >= N * 128) return;
  int n = i >> 7, c = i & 127;
  const int* t = trip + n * 4;
  float acc = bd[c];
  acc += (float)t[0] * Wd[c] + (float)t[1] * Wd[128 + c] +
         (float)t[2] * Wd[256 + c] + (float)t[3] * Wd[384 + c];
  x[i] = __float2bfloat16(acc);
}

// ---------------- bf16 MFMA GEMM: head-major planed output -----------------------
// COLSUM: fused column-sum (M=128 only).  COEF: fused es/ed attention coefficients
template <bool BIAS, bool COLSUM, bool COEF>
__global__ void k_gemm_mfma(const __hip_bfloat16* __restrict__ A,
                            const __hip_bfloat16* __restrict__ Bt,
                            const float* __restrict__ bias,
                            __hip_bfloat16* __restrict__ Cb,
                            float* __restrict__ colsum,
                            const float* __restrict__ as_, const float* __restrict__ ad_,
                            float* __restrict__ es, float* __restrict__ ed,
                            int Nr, int K, int M) {
  __shared__ short As[64 * 40];
  __shared__ short Bs[64 * 40];
  int tid = threadIdx.x;
  int lane = tid & 63, wid = tid >> 6;
  int wr = wid >> 1, wc = wid & 1;
  int lrow = lane & 15;
  int row0 = blockIdx.y * 64, col0 = blockIdx.x * 64;

  int arow = tid >> 2, akc = tid & 3;
  int grow = row0 + arow; if (grow >= Nr) grow = Nr - 1;
  const __hip_bfloat16* agp = A + (size_t)grow * K + akc * 8;
  const __hip_bfloat16* bgp = Bt + (size_t)(col0 + arow) * K + akc * 8;
  short* asp = &As[arow * 40 + akc * 8];
  short* bsp = &Bs[arow * 40 + akc * 8];

  f32x4 acc00 = {0.f,0.f,0.f,0.f}, acc01 = acc00, acc10 = acc00, acc11 = acc00;

  int lkc = lane >> 4;
  const short* a0p = &As[(wr * 32 + lrow) * 40 + lkc * 8];
  const short* a1p = &As[(wr * 32 + 16 + lrow) * 40 + lkc * 8];
  const short* b0p = &Bs[(wc * 32 + lrow) * 40 + lkc * 8];
  const short* b1p = &Bs[(wc * 32 + 16 + lrow) * 40 + lkc * 8];

  short8v av = *(const short8v*)agp;
  short8v bv = *(const short8v*)bgp;
  for (int k0 = 0; k0 < K; k0 += 32) {
    __syncthreads();
    *(short8v*)asp = av;
    *(short8v*)bsp = bv;
    __syncthreads();
    if (k0 + 32 < K) {
      av = *(const short8v*)(agp + k0 + 32);
      bv = *(const short8v*)(bgp + k0 + 32);
    }
    short8v a0 = *(const short8v*)a0p;
    short8v a1 = *(const short8v*)a1p;
    short8v b0 = *(const short8v*)b0p;
    short8v b1 = *(const short8v*)b1p;
    acc00 = __builtin_amdgcn_mfma_f32_16x16x32_bf16(a0, b0, acc00, 0, 0, 0);
    acc01 = __builtin_amdgcn_mfma_f32_16x16x32_bf16(a0, b1, acc01, 0, 0, 0);
    acc10 = __builtin_amdgcn_mfma_f32_16x16x32_bf16(a1, b0, acc10, 0, 0, 0);
    acc11 = __builtin_amdgcn_mfma_f32_16x16x32_bf16(a1, b1, acc11, 0, 0, 0);
  }

  // C/D layout (m89): col = lane&15, row = (lane>>4)*4 + r
  int rbase = row0 + wr * 32 + (lane >> 4) * 4;
  int cbase = col0 + wc * 32 + lrow;
  int hplane = col0 >> 7;
  float part0 = 0.f, part1 = 0.f;
  float esp[2][4], edp[2][4];
  float as0, as1, ad0, ad1;
  if (COEF) {
#pragma unroll
    for (int m = 0; m < 2; ++m)
#pragma unroll
      for (int r = 0; r < 4; ++r) { esp[m][r] = 0.f; edp[m][r] = 0.f; }
    int ch0 = (cbase & 127);
    as0 = as_[hplane * 128 + ch0];
    as1 = as_[hplane * 128 + ch0 + 16];
    ad0 = ad_[hplane * 128 + ch0];
    ad1 = ad_[hplane * 128 + ch0 + 16];
  }
#pragma unroll
  for (int m = 0; m < 2; ++m) {
#pragma unroll
    for (int n = 0; n < 2; ++n) {
      f32x4 acc = m == 0 ? (n == 0 ? acc00 : acc01) : (n == 0 ? acc10 : acc11);
      int col = cbase + n * 16;
      int plane = col >> 7, ch = col & 127;
      float bv2 = BIAS ? bias[col] : 0.f;
      __hip_bfloat16* cp = Cb + (size_t)plane * Nr * 128 + ch;
#pragma unroll
      for (int r = 0; r < 4; ++r) {
        int grow2 = rbase + m * 16 + r;
        if (grow2 >= Nr) continue;
        float v = acc[r] + bv2;
        cp[(size_t)grow2 * 128] = __float2bfloat16(v);
        if (COLSUM) { if (n == 0) part0 += v; else part1 += v; }
        if (COEF) {
          esp[m][r] += v * (n == 0 ? as0 : as1);
          edp[m][r] += v * (n == 0 ? ad0 : ad1);
        }
      }
    }
  }
  if (COLSUM) {
    part0 += __shfl_xor(part0, 16); part0 += __shfl_xor(part0, 32);
    part1 += __shfl_xor(part1, 16); part1 += __shfl_xor(part1, 32);
    if (lane < 16) {
      atomicAdd(&colsum[cbase], part0);
      atomicAdd(&colsum[cbase + 16], part1);
    }
  }
  if (COEF) {
#pragma unroll
    for (int m = 0; m < 2; ++m) {
#pragma unroll
      for (int r = 0; r < 4; ++r) {
        float e = esp[m][r], d = edp[m][r];
        e += __shfl_xor(e, 1); e += __shfl_xor(e, 2);
        e += __shfl_xor(e, 4); e += __shfl_xor(e, 8);
        d += __shfl_xor(d, 1); d += __shfl_xor(d, 2);
        d += __shfl_xor(d, 4); d += __shfl_xor(d, 8);
        if ((lane & 15) == 0) {
          int grow2 = rbase + m * 16 + r;
          if (grow2 < Nr) {
            atomicAdd(&es[(size_t)hplane * Nr + grow2], e);
            atomicAdd(&ed[(size_t)hplane * Nr + grow2], d);
          }
        }
      }
    }
  }
}

// ---------------- wave-per-output GEMM: C = relu(A @ Bt^T + bias) ----------------
__global__ void k_dotmm(const float* __restrict__ A, const float* __restrict__ Bt,
                        const float* __restrict__ bias, float* __restrict__ C,
                        int Nr, int K, int M) {
  int wid = (blockIdx.x * blockDim.x + threadIdx.x) >> 6;
  int lane = threadIdx.x & 63;
  if (wid >= Nr * M) return;
  int b = wid / M, m = wid % M;
  const float* ar = A + (size_t)b * K;
  const float* br = Bt + (size_t)m * K;
  float acc = 0.f;
  for (int k = lane * 2; k + 1 < K; k += 128) {
    float2 av = *(const float2*)(ar + k);
    float2 bv = *(const float2*)(br + k);
    acc += av.x * bv.x + av.y * bv.y;
  }
#pragma unroll
  for (int off = 32; off; off >>= 1) acc += __shfl_xor(acc, off);
  if (lane == 0) C[wid] = fmaxf(acc + bias[m], 0.f);
}

// ---------------- CSR build ----------------
__global__ void k_scan(const int* __restrict__ deg, int* __restrict__ rowptr, int N) {
  __shared__ int part[1024];
  int t = threadIdx.x;
  int chunk = (N + 1023) >> 10;
  int b0 = t * chunk, b1 = min(N, b0 + chunk);
  int s = 0;
  for (int i = b0; i < b1; i++) s += deg[i];
  part[t] = s;
  __syncthreads();
  for (int off = 1; off < 1024; off <<= 1) {
    int v = (t >= off) ? part[t - off] : 0;
    __syncthreads();
    part[t] += v;
    __syncthreads();
  }
  int run = (t == 0) ? 0 : part[t - 1];
  for (int i = b0; i < b1; i++) { rowptr[i] = run; run += deg[i]; }
  if (b1 == N) rowptr[N] = run;
}

__global__ void k_fill_adj(const int* __restrict__ src0, const int* __restrict__ dst0,
                           const int* __restrict__ rowptr, int* __restrict__ cursor,
                           int* __restrict__ adj, int E) {
  int e = blockIdx.x * 256 + threadIdx.x;
  if (e >= E) return;
  int s = src0[e], d = dst0[e];
  if (s != d) {
    int pos = rowptr[d] + atomicAdd(&cursor[d], 1);
    adj[pos] = s;
  }
}

// one edge, all H heads: packed broadcast words ks (s | bf16(p4)), k01 (p0,p1), k23 (p2,p3)
template <int H>
__device__ __forceinline__ void accE(const char* xbase, size_t plane, int loff,
                                     unsigned ks, unsigned k01, unsigned k23,
                                     float a[H][2]) {
  size_t row = (size_t)(ks & 0x7FFFu) * 256 + loff;
  float p[H];
  p[0] = __uint_as_float(k01 & 0xFFFF0000u);
  if (H > 1) p[1] = __uint_as_float(k01 << 16);
  if (H > 2) p[2] = __uint_as_float(k23 & 0xFFFF0000u);
  if (H > 3) p[3] = __uint_as_float(k23 << 16);
  if (H > 4) p[4] = __uint_as_float(ks & 0xFFFF0000u);
#pragma unroll
  for (int h = 0; h < H; ++h) {
    unsigned u = *(const unsigned*)(xbase + (size_t)h * plane + row);
    a[h][0] += p[h] * bf2lo(u);
    a[h][1] += p[h] * bf2hi(u);
  }
}

// ---------------- head-merged GAT aggregation: one wave per NODE, all H heads ----------
// NOTE: requires N < 32768 (15-bit packed row index); harness N = 20000.
template <int H>
__global__ void k_gat_gather(const int* __restrict__ rowptr, const int* __restrict__ adj,
                             const float* __restrict__ es, const float* __restrict__ ed,
                             const __hip_bfloat16* __restrict__ xh,
                             const float* __restrict__ bias,
                             __hip_bfloat16* __restrict__ gout, int N) {
  int nb = gridDim.x, bx = blockIdx.x;
  int sb = ((nb & 7) == 0) ? ((bx & 7) * (nb >> 3) + (bx >> 3)) : bx;
  int n = sb * 4 + (threadIdx.x >> 6);
  int lane = threadIdx.x & 63;
  if (n >= N) return;
  int base = rowptr[n];
  int deg = rowptr[n + 1] - base;
  const char* xbase = (const char*)xh;
  const size_t plane = (size_t)N * 256;
  int loff = lane * 4;

  float edn[H], vself[H], pself[H], psum[H];
  float a[H][2];
#pragma unroll
  for (int h = 0; h < H; ++h) {
    edn[h] = ed[(size_t)h * N + n];
    vself[h] = leaky(es[(size_t)h * N + n] + edn[h]);
    a[h][0] = 0.f; a[h][1] = 0.f;
    psum[h] = 0.f;
  }

  if (deg <= 64) {
    // fast path: single fused pass
    int s = 0; bool val = lane < deg;
    if (val) s = adj[base + lane];
    float p[H];
#pragma unroll
    for (int h = 0; h < H; ++h) {
      float v = val ? leaky(es[(size_t)h * N + s] + edn[h]) : -3e38f;
      float mh = fmaxf(vself[h], v);
#pragma unroll
      for (int off = 32; off; off >>= 1) mh = fmaxf(mh, __shfl_xor(mh, off));
      p[h] = val ? __expf(v - mh) : 0.f;
      pself[h] = __expf(vself[h] - mh);
      psum[h] = p[h];
    }
    unsigned ks = (unsigned)s;
    if (H > 4) ks |= (__float_as_uint(p[H > 4 ? 4 : 0]) & 0xFFFF0000u);
    unsigned k01 = (__float_as_uint(p[0]) & 0xFFFF0000u);
    if (H > 1) k01 |= (__float_as_uint(p[1]) >> 16);
    unsigned k23 = 0;
    if (H > 2) k23 = (__float_as_uint(p[2]) & 0xFFFF0000u);
    if (H > 3) k23 |= (__float_as_uint(p[3]) >> 16);
    for (int j = 0; j < deg; j += 2) {
      unsigned ks0 = __builtin_amdgcn_readlane(ks, j);
      unsigned k010 = __builtin_amdgcn_readlane(k01, j);
      unsigned k230 = __builtin_amdgcn_readlane(k23, j);
      unsigned ks1 = __builtin_amdgcn_readlane(ks, j + 1);
      unsigned k011 = __builtin_amdgcn_readlane(k01, j + 1);
      unsigned k231 = __builtin_amdgcn_readlane(k23, j + 1);
      accE<H>(xbase, plane, loff, ks0, k010, k230, a);
      accE<H>(xbase, plane, loff, ks1, k011, k231, a);
    }
  } else {
    float mh[H];
#pragma unroll
    for (int h = 0; h < H; ++h) mh[h] = vself[h];
    for (int i = lane; i < deg; i += 64) {
      int s = adj[base + i];
#pragma unroll
      for (int h = 0; h < H; ++h)
        mh[h] = fmaxf(mh[h], leaky(es[(size_t)h * N + s] + edn[h]));
    }
#pragma unroll
    for (int h = 0; h < H; ++h) {
#pragma unroll
      for (int off = 32; off; off >>= 1) mh[h] = fmaxf(mh[h], __shfl_xor(mh[h], off));
      pself[h] = __expf(vself[h] - mh[h]);
    }
    for (int c = 0; c < deg; c += 64) {
      int i = c + lane;
      int s = 0; float p[H];
#pragma unroll
      for (int h = 0; h < H; ++h) p[h] = 0.f;
      if (i < deg) {
        s = adj[base + i];
#pragma unroll
        for (int h = 0; h < H; ++h) {
          p[h] = __expf(leaky(es[(size_t)h * N + s] + edn[h]) - mh[h]);
          psum[h] += p[h];
        }
      }
      unsigned ks = (unsigned)s;
      if (H > 4) ks |= (__float_as_uint(p[H > 4 ? 4 : 0]) & 0xFFFF0000u);
      unsigned k01 = (__float_as_uint(p[0]) & 0xFFFF0000u);
      if (H > 1) k01 |= (__float_as_uint(p[1]) >> 16);
      unsigned k23 = 0;
      if (H > 2) k23 = (__float_as_uint(p[2]) & 0xFFFF0000u);
      if (H > 3) k23 |= (__float_as_uint(p[3]) >> 16);
      int cnt = min(64, deg - c);
      for (int j = 0; j < cnt; j += 2) {
        unsigned ks0 = __builtin_amdgcn_readlane(ks, j);
        unsigned k010 = __builtin_amdgcn_readlane(k01, j);
        unsigned k230 = __builtin_amdgcn_readlane(k23, j);
        unsigned ks1 = __builtin_amdgcn_readlane(ks, j + 1);
        unsigned k011 = __builtin_amdgcn_readlane(k01, j + 1);
        unsigned k231 = __builtin_amdgcn_readlane(k23, j + 1);
        accE<H>(xbase, plane, loff, ks0, k010, k230, a);
        accE<H>(xbase, plane, loff, ks1, k011, k231, a);
      }
    }
  }

#pragma unroll
  for (int h = 0; h < H; ++h) {
    // self-loop (full-precision pself)
    unsigned u = *(const unsigned*)(xbase + (size_t)h * plane + (size_t)n * 256 + loff);
    a[h][0] += pself[h] * bf2lo(u);
    a[h][1] += pself[h] * bf2hi(u);
    float ps = psum[h];
#pragma unroll
    for (int off = 32; off; off >>= 1) ps += __shfl_xor(ps, off);
    ps += pself[h];
    float inv = 1.f / ps;
    float2 bv = ((const float2*)(bias + h * 128))[lane];
    float o0 = a[h][0] * inv + bv.x;
    float o1 = a[h][1] * inv + bv.y;
    o0 = o0 > 0.f ? o0 : __expf(o0) - 1.f;
    o1 = o1 > 0.f ? o1 : __expf(o1) - 1.f;
    __hip_bfloat162 r;
    r.x = __float2bfloat16(o0);
    r.y = __float2bfloat16(o1);
    ((__hip_bfloat162*)(gout + (size_t)n * (H * 128) + h * 128))[lane] = r;
  }
}

// single block head MLP -> vvec[384]
__global__ void k_head(const float* __restrict__ colsum, const float* __restrict__ Wfc,
                       const float* __restrict__ bfc, const float* __restrict__ Whg,
                       const float* __restrict__ bhg, const float* __restrict__ Wv,
                       const float* __restrict__ bv, float* __restrict__ vvec, float invN) {
  __shared__ float h[128], t1[256], hg[128];
  int t = threadIdx.x;  // 256
  if (t < 128) h[t] = colsum[t] * invN;
  __syncthreads();
  float acc = bfc[t];
  for (int k = 0; k < 128; k++) acc += h[k] * Wfc[k * 256 + t];
  t1[t] = fmaxf(acc, 0.f);
  __syncthreads();
  if (t < 128) {
    float a2 = bhg[t];
    for (int k = 0; k < 256; k++) a2 += t1[k] * Whg[k * 128 + t];
    hg[t] = a2;
  }
  __syncthreads();
  for (int j = t; j < 384; j += 256) {
    float a3 = bv[j];
    for (int k = 0; k < 128; k++) a3 += hg[k] * Wv[k * 384 + j];
    vvec[j] = fmaxf(a3, 0.f);
  }
}

// per-batch-row BAN tail
__global__ void k_fused(const float* __restrict__ vvec, const float* __restrict__ q,
                        const float* __restrict__ hmat, const float* __restrict__ hbias,
                        float* __restrict__ logits) {
  int b = blockIdx.x, c = threadIdx.x;  // 128 threads
  __shared__ float red[128];
  float t[3];
  float part = 0.f;
#pragma unroll
  for (int j = 0; j < 3; j++) {
    int k = c * 3 + j;
    float hs = hmat[k] + hmat[384 + k] + hmat[768 + k] + hmat[1152 + k];
    t[j] = vvec[k] * q[(size_t)b * 384 + k];
    part += hs * t[j];
  }
  red[c] = part;
  __syncthreads();
  for (int s = 64; s > 0; s >>= 1) {
    if (c < s) red[c] += red[c + s];
    __syncthreads();
  }
  float attsum = red[0] + (hbias[0] + hbias[1] + hbias[2] + hbias[3]);
  logits[(size_t)b * 128 + c] = attsum * (t[0] + t[1] + t[2]);
}

// batchnorm over batch dim (biased var), one block per channel c
__global__ void k_bn(const float* __restrict__ logits, const float* __restrict__ gamma,
                     const float* __restrict__ beta, float* __restrict__ out, int B) {
  int c = blockIdx.x, b = threadIdx.x;  // B threads
  __shared__ float s1[256], s2[256];
  float v = logits[(size_t)b * 128 + c];
  s1[b] = v; s2[b] = v * v;
  __syncthreads();
  for (int s = B / 2; s > 0; s >>= 1) {
    if (b < s) { s1[b] += s1[b + s]; s2[b] += s2[b + s]; }
    __syncthreads();
  }
  float mu = s1[0] / B;
  float var = s2[0] / B - mu * mu;
  out[(size_t)b * 128 + c] = (v - mu) * rsqrtf(var + 1e-5f) * gamma[c] + beta[c];
}

extern "C" void kernel_launch(void* const* d_in, const int* in_sizes, int n_in,
                              void* d_out, int out_size, void* d_ws, size_t ws_size,
                              hipStream_t stream) {
  const float* cell = (const float*)d_in[0];
  const float* Wd   = (const float*)d_in[1];
  const float* bd   = (const float*)d_in[2];
  const float* W1   = (const float*)d_in[3];
  const float* a1s  = (const float*)d_in[4];
  const float* a1d  = (const float*)d_in[5];
  const float* b1   = (const float*)d_in[6];
  const float* Wl1  = (const float*)d_in[7];
  const float* bl1  = (const float*)d_in[8];
  const float* W2   = (const float*)d_in[9];
  const float* a2s  = (const float*)d_in[10];
  const float* a2d  = (const float*)d_in[11];
  const float* b2   = (const float*)d_in[12];
  const float* Wl2  = (const float*)d_in[13];
  const float* bl2  = (const float*)d_in[14];
  const float* Wfc  = (const float*)d_in[15];
  const float* bfc  = (const float*)d_in[16];
  const float* Whg  = (const float*)d_in[17];
  const float* bhg  = (const float*)d_in[18];
  const float* Wc   = (const float*)d_in[19];
  const float* bc   = (const float*)d_in[20];
  const float* Wv   = (const float*)d_in[21];
  const float* bv   = (const float*)d_in[22];
  const float* Wq   = (const float*)d_in[23];
  const float* bq   = (const float*)d_in[24];
  const float* hmat = (const float*)d_in[25];
  const float* hbias= (const float*)d_in[26];
  const float* gamma= (const float*)d_in[27];
  const float* beta = (const float*)d_in[28];
  const int* trip   = (const int*)d_in[29];
  const int* eidx   = (const int*)d_in[30];

  const int N = in_sizes[29] / 4;     // 20000
  const int E = in_sizes[30] / 2;     // 500000
  const int B = in_sizes[0] / 954;    // 256
  float* out = (float*)d_out;

  // ---------------- workspace layout: bf16 region first (16B aligned) ----------------
  __hip_bfloat16* xb    = (__hip_bfloat16*)d_ws;      // N*128
  __hip_bfloat16* xhb   = xb + (size_t)N * 128;       // N*640  (head-major [H][N][128])
  __hip_bfloat16* goutb = xhb + (size_t)N * 640;      // N*640  (row-major [N][H*128])
  __hip_bfloat16* h1b   = goutb + (size_t)N * 640;    // N*128
  __hip_bfloat16* h2b   = h1b + (size_t)N * 128;      // N*128
  __hip_bfloat16* W1t   = h2b + (size_t)N * 128;      // 512*128
  __hip_bfloat16* Wl1t  = W1t + 512 * 128;            // 128*512
  __hip_bfloat16* W2t   = Wl1t + 128 * 512;           // 640*128
  __hip_bfloat16* Wl2t  = W2t + 640 * 128;            // 128*640
  // f32 region: per-layer es/ed (contiguous 18N for one-shot zeroing)
  float* es1    = (float*)(Wl2t + 128 * 640);  // 4N
  float* ed1    = es1 + (size_t)4 * N;         // 4N
  float* es2    = ed1 + (size_t)4 * N;         // 5N
  float* ed2    = es2 + (size_t)5 * N;         // 5N
  float* colsum = ed2 + (size_t)5 * N;         // 128
  float* cbuf   = colsum + 128;                // B*128
  float* qbuf   = cbuf + (size_t)B * 128;      // B*384
  float* vvec   = qbuf + (size_t)B * 384;      // 384
  float* logits = vvec + 384;                  // B*128
  float* Wct    = logits + (size_t)B * 128;    // 128*954
  float* Wqt    = Wct + 128 * 954;             // 384*128
  // int region
  int* rowptr   = (int*)(Wqt + 384 * 128);     // N+1
  int* degb     = rowptr + (N + 1);            // N
  int* cursor   = degb + N;                    // N (contiguous after degb)
  int* adj      = cursor + N;                  // E

  const int* src0 = eidx;
  const int* dst0 = eidx + E;

  // weight transposes + zeroing of colsum/degb/cursor/es/ed in one launch
  {
    int tot = 128*512 + 512*128 + 128*640 + 640*128 + 954*128 + 128*384
              + 128 + 2 * N + 18 * N;
    k_prep<<<CDIV(tot, 256), 256, 0, stream>>>(W1, W1t, Wl1, Wl1t, W2, W2t, Wl2, Wl2t,
                                               Wc, Wct, Wq, Wqt, colsum, degb, es1, N);
  }

  // degree count + drug linear in one dispatch
  k_degdrug<<<CDIV(E + N * 128, 256), 256, 0, stream>>>(src0, dst0, degb, E,
                                                        trip, Wd, bd, xb, N);
  k_scan<<<1, 1024, 0, stream>>>(degb, rowptr, N);
  k_fill_adj<<<CDIV(E, 256), 256, 0, stream>>>(src0, dst0, rowptr, cursor, adj, E);

  // ---------------- GAT1 (H=4) ----------------
  {
    dim3 g(512 / 64, CDIV(N, 64));
    k_gemm_mfma<false, false, true><<<g, 256, 0, stream>>>(
        xb, W1t, nullptr, xhb, nullptr, a1s, a1d, es1, ed1, N, 128, 512);
  }
  k_gat_gather<4><<<CDIV(N, 4), 256, 0, stream>>>(rowptr, adj, es1, ed1, xhb, b1, goutb, N);
  {
    dim3 g(128 / 64, CDIV(N, 64));
    k_gemm_mfma<true, true, false><<<g, 256, 0, stream>>>(
        goutb, Wl1t, bl1, h1b, colsum, nullptr, nullptr, nullptr, nullptr, N, 512, 128);
  }

  // ---------------- GAT2 (H=5) ----------------
  {
    dim3 g(640 / 64, CDIV(N, 64));
    k_gemm_mfma<false, false, true><<<g, 256, 0, stream>>>(
        h1b, W2t, nullptr, xhb, nullptr, a2s, a2d, es2, ed2, N, 128, 640);
  }
  k_gat_gather<5><<<CDIV(N, 4), 256, 0, stream>>>(rowptr, adj, es2, ed2, xhb, b2, goutb, N);
  {
    dim3 g(128 / 64, CDIV(N, 64));
    k_gemm_mfma<true, true, false><<<g, 256, 0, stream>>>(
        goutb, Wl2t, bl2, h2b, colsum, nullptr, nullptr, nullptr, nullptr, N, 640, 128);
  }

  // ---------------- head + BAN + BN ----------------
  k_head<<<1, 256, 0, stream>>>(colsum, Wfc, bfc, Whg, bhg, Wv, bv, vvec, 1.0f / N);
  k_dotmm<<<CDIV(B * 128, 4), 256, 0, stream>>>(cell, Wct, bc, cbuf, B, 954, 128);
  k_dotmm<<<CDIV(B * 384, 4), 256, 0, stream>>>(cbuf, Wqt, bq, qbuf, B, 128, 384);
  k_fused<<<B, 128, 0, stream>>>(vvec, qbuf, hmat, hbias, logits);
  k_bn<<<128, B, 0, stream>>>(logits, gamma, beta, out, B);
}

// Round 14
// 451.680 us; speedup vs baseline: 1.1424x; 1.1424x over previous
//
#include <hip/hip_runtime.h>
#include <hip/hip_bf16.h>
#include <math.h>

#define CDIV(a,b) (((a)+(b)-1)/(b))

typedef __attribute__((ext_vector_type(8))) short short8v;   // 8 bf16
typedef __attribute__((ext_vector_type(4))) float f32x4;

__device__ inline float bf2lo(unsigned u) { return __uint_as_float(u << 16); }
__device__ inline float bf2hi(unsigned u) { return __uint_as_float(u & 0xffff0000u); }
__device__ inline float leaky(float v) { return v > 0.f ? v : 0.2f * v; }

// ---------------- weight transposes + buffer zeroing in one launch ----------------
__global__ void k_prep(const float* __restrict__ W1, __hip_bfloat16* __restrict__ W1t,
                       const float* __restrict__ Wl1, __hip_bfloat16* __restrict__ Wl1t,
                       const float* __restrict__ W2, __hip_bfloat16* __restrict__ W2t,
                       const float* __restrict__ Wl2, __hip_bfloat16* __restrict__ Wl2t,
                       const float* __restrict__ Wc, float* __restrict__ Wct,
                       const float* __restrict__ Wq, float* __restrict__ Wqt,
                       float* __restrict__ colsum, int* __restrict__ degz,
                       float* __restrict__ esz, int N) {
  int i = blockIdx.x * 256 + threadIdx.x;
  const int n1 = 128 * 512, n2 = 512 * 128, n3 = 128 * 640, n4 = 640 * 128;
  const int n5 = 954 * 128, n6 = 128 * 384;
  if (i < n1) { int m = i / 128, k = i % 128; W1t[i] = __float2bfloat16(W1[(size_t)k * 512 + m]); return; }
  i -= n1;
  if (i < n2) { int m = i / 512, k = i % 512; Wl1t[i] = __float2bfloat16(Wl1[(size_t)k * 128 + m]); return; }
  i -= n2;
  if (i < n3) { int m = i / 128, k = i % 128; W2t[i] = __float2bfloat16(W2[(size_t)k * 640 + m]); return; }
  i -= n3;
  if (i < n4) { int m = i / 640, k = i % 640; Wl2t[i] = __float2bfloat16(Wl2[(size_t)k * 128 + m]); return; }
  i -= n4;
  if (i < n5) { int m = i / 954, k = i % 954; Wct[i] = Wc[(size_t)k * 128 + m]; return; }
  i -= n5;
  if (i < n6) { int m = i / 128, k = i % 128; Wqt[i] = Wq[(size_t)k * 384 + m]; return; }
  i -= n6;
  if (i < 128) { colsum[i] = 0.f; return; }
  i -= 128;
  if (i < 2 * N) { degz[i] = 0; return; }   // degb and cursor contiguous
  i -= 2 * N;
  if (i < 18 * N) { esz[i] = 0.f; return; } // es1(4N) ed1(4N) es2(5N) ed2(5N) contiguous
}

// ---------------- fused: degree count (first E threads) + drug linear (rest) ----------
__global__ void k_degdrug(const int* __restrict__ src0, const int* __restrict__ dst0,
                          int* __restrict__ deg, int E,
                          const int* __restrict__ trip, const float* __restrict__ Wd,
                          const float* __restrict__ bd, __hip_bfloat16* __restrict__ x,
                          int N) {
  int i = blockIdx.x * 256 + threadIdx.x;
  if (i < E) {
    int s = src0[i], d = dst0[i];
    if (s != d) atomicAdd(&deg[d], 1);
    return;
  }
  i -= E;
  if (i >= N * 128) return;
  int n = i >> 7, c = i & 127;
  const int* t = trip + n * 4;
  float acc = bd[c];
  acc += (float)t[0] * Wd[c] + (float)t[1] * Wd[128 + c] +
         (float)t[2] * Wd[256 + c] + (float)t[3] * Wd[384 + c];
  x[i] = __float2bfloat16(acc);
}

// ---------------- bf16 MFMA GEMM: head-major planed output -----------------------
// COLSUM: fused column-sum (M=128 only).  COEF: fused es/ed attention coefficients
template <bool BIAS, bool COLSUM, bool COEF>
__global__ void k_gemm_mfma(const __hip_bfloat16* __restrict__ A,
                            const __hip_bfloat16* __restrict__ Bt,
                            const float* __restrict__ bias,
                            __hip_bfloat16* __restrict__ Cb,
                            float* __restrict__ colsum,
                            const float* __restrict__ as_, const float* __restrict__ ad_,
                            float* __restrict__ es, float* __restrict__ ed,
                            int Nr, int K, int M) {
  __shared__ short As[64 * 40];
  __shared__ short Bs[64 * 40];
  int tid = threadIdx.x;
  int lane = tid & 63, wid = tid >> 6;
  int wr = wid >> 1, wc = wid & 1;
  int lrow = lane & 15;
  int row0 = blockIdx.y * 64, col0 = blockIdx.x * 64;

  int arow = tid >> 2, akc = tid & 3;
  int grow = row0 + arow; if (grow >= Nr) grow = Nr - 1;
  const __hip_bfloat16* agp = A + (size_t)grow * K + akc * 8;
  const __hip_bfloat16* bgp = Bt + (size_t)(col0 + arow) * K + akc * 8;
  short* asp = &As[arow * 40 + akc * 8];
  short* bsp = &Bs[arow * 40 + akc * 8];

  f32x4 acc00 = {0.f,0.f,0.f,0.f}, acc01 = acc00, acc10 = acc00, acc11 = acc00;

  int lkc = lane >> 4;
  const short* a0p = &As[(wr * 32 + lrow) * 40 + lkc * 8];
  const short* a1p = &As[(wr * 32 + 16 + lrow) * 40 + lkc * 8];
  const short* b0p = &Bs[(wc * 32 + lrow) * 40 + lkc * 8];
  const short* b1p = &Bs[(wc * 32 + 16 + lrow) * 40 + lkc * 8];

  short8v av = *(const short8v*)agp;
  short8v bv = *(const short8v*)bgp;
  for (int k0 = 0; k0 < K; k0 += 32) {
    __syncthreads();
    *(short8v*)asp = av;
    *(short8v*)bsp = bv;
    __syncthreads();
    if (k0 + 32 < K) {
      av = *(const short8v*)(agp + k0 + 32);
      bv = *(const short8v*)(bgp + k0 + 32);
    }
    short8v a0 = *(const short8v*)a0p;
    short8v a1 = *(const short8v*)a1p;
    short8v b0 = *(const short8v*)b0p;
    short8v b1 = *(const short8v*)b1p;
    acc00 = __builtin_amdgcn_mfma_f32_16x16x32_bf16(a0, b0, acc00, 0, 0, 0);
    acc01 = __builtin_amdgcn_mfma_f32_16x16x32_bf16(a0, b1, acc01, 0, 0, 0);
    acc10 = __builtin_amdgcn_mfma_f32_16x16x32_bf16(a1, b0, acc10, 0, 0, 0);
    acc11 = __builtin_amdgcn_mfma_f32_16x16x32_bf16(a1, b1, acc11, 0, 0, 0);
  }

  // C/D layout (m89): col = lane&15, row = (lane>>4)*4 + r
  int rbase = row0 + wr * 32 + (lane >> 4) * 4;
  int cbase = col0 + wc * 32 + lrow;
  int hplane = col0 >> 7;
  float part0 = 0.f, part1 = 0.f;
  float esp[2][4], edp[2][4];
  float as0, as1, ad0, ad1;
  if (COEF) {
#pragma unroll
    for (int m = 0; m < 2; ++m)
#pragma unroll
      for (int r = 0; r < 4; ++r) { esp[m][r] = 0.f; edp[m][r] = 0.f; }
    int ch0 = (cbase & 127);
    as0 = as_[hplane * 128 + ch0];
    as1 = as_[hplane * 128 + ch0 + 16];
    ad0 = ad_[hplane * 128 + ch0];
    ad1 = ad_[hplane * 128 + ch0 + 16];
  }
#pragma unroll
  for (int m = 0; m < 2; ++m) {
#pragma unroll
    for (int n = 0; n < 2; ++n) {
      f32x4 acc = m == 0 ? (n == 0 ? acc00 : acc01) : (n == 0 ? acc10 : acc11);
      int col = cbase + n * 16;
      int plane = col >> 7, ch = col & 127;
      float bv2 = BIAS ? bias[col] : 0.f;
      __hip_bfloat16* cp = Cb + (size_t)plane * Nr * 128 + ch;
#pragma unroll
      for (int r = 0; r < 4; ++r) {
        int grow2 = rbase + m * 16 + r;
        if (grow2 >= Nr) continue;
        float v = acc[r] + bv2;
        cp[(size_t)grow2 * 128] = __float2bfloat16(v);
        if (COLSUM) { if (n == 0) part0 += v; else part1 += v; }
        if (COEF) {
          esp[m][r] += v * (n == 0 ? as0 : as1);
          edp[m][r] += v * (n == 0 ? ad0 : ad1);
        }
      }
    }
  }
  if (COLSUM) {
    part0 += __shfl_xor(part0, 16); part0 += __shfl_xor(part0, 32);
    part1 += __shfl_xor(part1, 16); part1 += __shfl_xor(part1, 32);
    if (lane < 16) {
      atomicAdd(&colsum[cbase], part0);
      atomicAdd(&colsum[cbase + 16], part1);
    }
  }
  if (COEF) {
#pragma unroll
    for (int m = 0; m < 2; ++m) {
#pragma unroll
      for (int r = 0; r < 4; ++r) {
        float e = esp[m][r], d = edp[m][r];
        e += __shfl_xor(e, 1); e += __shfl_xor(e, 2);
        e += __shfl_xor(e, 4); e += __shfl_xor(e, 8);
        d += __shfl_xor(d, 1); d += __shfl_xor(d, 2);
        d += __shfl_xor(d, 4); d += __shfl_xor(d, 8);
        if ((lane & 15) == 0) {
          int grow2 = rbase + m * 16 + r;
          if (grow2 < Nr) {
            atomicAdd(&es[(size_t)hplane * Nr + grow2], e);
            atomicAdd(&ed[(size_t)hplane * Nr + grow2], d);
          }
        }
      }
    }
  }
}

// ---------------- CSR build ----------------
__global__ void k_scan(const int* __restrict__ deg, int* __restrict__ rowptr, int N) {
  __shared__ int part[1024];
  int t = threadIdx.x;
  int chunk = (N + 1023) >> 10;
  int b0 = t * chunk, b1 = min(N, b0 + chunk);
  int s = 0;
  for (int i = b0; i < b1; i++) s += deg[i];
  part[t] = s;
  __syncthreads();
  for (int off = 1; off < 1024; off <<= 1) {
    int v = (t >= off) ? part[t - off] : 0;
    __syncthreads();
    part[t] += v;
    __syncthreads();
  }
  int run = (t == 0) ? 0 : part[t - 1];
  for (int i = b0; i < b1; i++) { rowptr[i] = run; run += deg[i]; }
  if (b1 == N) rowptr[N] = run;
}

__global__ void k_fill_adj(const int* __restrict__ src0, const int* __restrict__ dst0,
                           const int* __restrict__ rowptr, int* __restrict__ cursor,
                           int* __restrict__ adj, int E) {
  int e = blockIdx.x * 256 + threadIdx.x;
  if (e >= E) return;
  int s = src0[e], d = dst0[e];
  if (s != d) {
    int pos = rowptr[d] + atomicAdd(&cursor[d], 1);
    adj[pos] = s;
  }
}

// 8-edge broadcast accumulate with (s,p) PACKED per lane:
//   pk = (bf16bits(p) << 16) | s,  requires s < 32768 and p >= 0.
__device__ __forceinline__ void acc8p(const char* xbase, int loff, unsigned pk, int j,
                                      float& a0, float& a1) {
  unsigned k0 = __builtin_amdgcn_readlane(pk, j);
  unsigned k1 = __builtin_amdgcn_readlane(pk, j + 1);
  unsigned k2 = __builtin_amdgcn_readlane(pk, j + 2);
  unsigned k3 = __builtin_amdgcn_readlane(pk, j + 3);
  unsigned k4 = __builtin_amdgcn_readlane(pk, j + 4);
  unsigned k5 = __builtin_amdgcn_readlane(pk, j + 5);
  unsigned k6 = __builtin_amdgcn_readlane(pk, j + 6);
  unsigned k7 = __builtin_amdgcn_readlane(pk, j + 7);
  unsigned u0 = *(const unsigned*)(xbase + (size_t)(k0 & 0x7FFFu) * 256 + loff);
  unsigned u1 = *(const unsigned*)(xbase + (size_t)(k1 & 0x7FFFu) * 256 + loff);
  unsigned u2 = *(const unsigned*)(xbase + (size_t)(k2 & 0x7FFFu) * 256 + loff);
  unsigned u3 = *(const unsigned*)(xbase + (size_t)(k3 & 0x7FFFu) * 256 + loff);
  unsigned u4 = *(const unsigned*)(xbase + (size_t)(k4 & 0x7FFFu) * 256 + loff);
  unsigned u5 = *(const unsigned*)(xbase + (size_t)(k5 & 0x7FFFu) * 256 + loff);
  unsigned u6 = *(const unsigned*)(xbase + (size_t)(k6 & 0x7FFFu) * 256 + loff);
  unsigned u7 = *(const unsigned*)(xbase + (size_t)(k7 & 0x7FFFu) * 256 + loff);
  float p0 = __uint_as_float(k0 & 0xFFFF0000u);
  float p1 = __uint_as_float(k1 & 0xFFFF0000u);
  float p2 = __uint_as_float(k2 & 0xFFFF0000u);
  float p3 = __uint_as_float(k3 & 0xFFFF0000u);
  float p4 = __uint_as_float(k4 & 0xFFFF0000u);
  float p5 = __uint_as_float(k5 & 0xFFFF0000u);
  float p6 = __uint_as_float(k6 & 0xFFFF0000u);
  float p7 = __uint_as_float(k7 & 0xFFFF0000u);
  a0 += p0 * bf2lo(u0); a1 += p0 * bf2hi(u0);
  a0 += p1 * bf2lo(u1); a1 += p1 * bf2hi(u1);
  a0 += p2 * bf2lo(u2); a1 += p2 * bf2hi(u2);
  a0 += p3 * bf2lo(u3); a1 += p3 * bf2hi(u3);
  a0 += p4 * bf2lo(u4); a1 += p4 * bf2hi(u4);
  a0 += p5 * bf2lo(u5); a1 += p5 * bf2hi(u5);
  a0 += p6 * bf2lo(u6); a1 += p6 * bf2hi(u6);
  a0 += p7 * bf2lo(u7); a1 += p7 * bf2hi(u7);
}

// ---------------- fused GAT aggregation: one wave per (node, head), 2D grid ----------
// NOTE: requires N < 32768 (15-bit packed row index); harness N = 20000.
__global__ void k_gat_gather(const int* __restrict__ rowptr, const int* __restrict__ adj,
                             const float* __restrict__ es, const float* __restrict__ ed,
                             const __hip_bfloat16* __restrict__ xh,
                             const float* __restrict__ bias,
                             __hip_bfloat16* __restrict__ gout, int N, int H) {
  int nb = gridDim.x, bx = blockIdx.x;
  int sb = ((nb & 7) == 0) ? ((bx & 7) * (nb >> 3) + (bx >> 3)) : bx;
  int h = blockIdx.y;
  int n = sb * 4 + (threadIdx.x >> 6);
  int lane = threadIdx.x & 63;
  if (n >= N) return;
  int base = rowptr[n];
  int deg = rowptr[n + 1] - base;
  const float* esh = es + (size_t)h * N;
  float edn = ed[(size_t)h * N + n];
  float vself = leaky(esh[n] + edn);
  const char* xbase = (const char*)xh + (size_t)h * N * 256;
  int loff = lane * 4;

  float a0 = 0.f, a1 = 0.f;
  float psum = 0.f, pself, m;

  if (deg <= 64) {
    int s = 0; float v = -3e38f;
    if (lane < deg) { s = adj[base + lane]; v = leaky(esh[s] + edn); }
    m = fmaxf(vself, v);
#pragma unroll
    for (int off = 32; off; off >>= 1) m = fmaxf(m, __shfl_xor(m, off));
    float p = (lane < deg) ? __expf(v - m) : 0.f;
    pself = __expf(vself - m);
    psum = p;
    unsigned pk = (__float_as_uint(p) & 0xFFFF0000u) | (unsigned)s;
    for (int j = 0; j < deg; j += 8) acc8p(xbase, loff, pk, j, a0, a1);
  } else {
    m = vself;
    for (int i = lane; i < deg; i += 64) {
      int s = adj[base + i];
      m = fmaxf(m, leaky(esh[s] + edn));
    }
#pragma unroll
    for (int off = 32; off; off >>= 1) m = fmaxf(m, __shfl_xor(m, off));
    pself = __expf(vself - m);
    for (int c = 0; c < deg; c += 64) {
      int i = c + lane;
      int s = 0; float p = 0.f;
      if (i < deg) {
        s = adj[base + i];
        p = __expf(leaky(esh[s] + edn) - m);
        psum += p;
      }
      unsigned pk = (__float_as_uint(p) & 0xFFFF0000u) | (unsigned)s;
      int cnt = min(64, deg - c);
      for (int j = 0; j < cnt; j += 8) acc8p(xbase, loff, pk, j, a0, a1);
    }
  }

  {
    unsigned u = *(const unsigned*)(xbase + (size_t)n * 256 + loff);
    a0 += pself * bf2lo(u);
    a1 += pself * bf2hi(u);
  }
#pragma unroll
  for (int off = 32; off; off >>= 1) psum += __shfl_xor(psum, off);
  psum += pself;
  float inv = 1.f / psum;
  float2 bv = ((const float2*)(bias + h * 128))[lane];
  float o0 = a0 * inv + bv.x;
  float o1 = a1 * inv + bv.y;
  o0 = o0 > 0.f ? o0 : __expf(o0) - 1.f;
  o1 = o1 > 0.f ? o1 : __expf(o1) - 1.f;
  __hip_bfloat162 r;
  r.x = __float2bfloat16(o0);
  r.y = __float2bfloat16(o1);
  ((__hip_bfloat162*)(gout + (size_t)n * (H * 128) + h * 128))[lane] = r;
}

// ---------------- head MLP (block 0) + cell dotmm (blocks 1..) in one launch ----------
__global__ void k_headdot(const float* __restrict__ colsum, const float* __restrict__ Wfc,
                          const float* __restrict__ bfc, const float* __restrict__ Whg,
                          const float* __restrict__ bhg, const float* __restrict__ Wv,
                          const float* __restrict__ bv, float* __restrict__ vvec, float invN,
                          const float* __restrict__ cell, const float* __restrict__ Wct,
                          const float* __restrict__ bc, float* __restrict__ cbuf,
                          int Nr, int K, int M) {
  if (blockIdx.x == 0) {
    __shared__ float h[128], t1[256], hg[128];
    int t = threadIdx.x;  // 256
    if (t < 128) h[t] = colsum[t] * invN;
    __syncthreads();
    float acc = bfc[t];
    for (int k = 0; k < 128; k++) acc += h[k] * Wfc[k * 256 + t];
    t1[t] = fmaxf(acc, 0.f);
    __syncthreads();
    if (t < 128) {
      float a2 = bhg[t];
      for (int k = 0; k < 256; k++) a2 += t1[k] * Whg[k * 128 + t];
      hg[t] = a2;
    }
    __syncthreads();
    for (int j = t; j < 384; j += 256) {
      float a3 = bv[j];
      for (int k = 0; k < 128; k++) a3 += hg[k] * Wv[k * 384 + j];
      vvec[j] = fmaxf(a3, 0.f);
    }
    return;
  }
  int wid = (int)(blockIdx.x - 1) * 4 + (threadIdx.x >> 6);
  int lane = threadIdx.x & 63;
  if (wid >= Nr * M) return;
  int b = wid / M, m = wid % M;
  const float* ar = cell + (size_t)b * K;
  const float* br = Wct + (size_t)m * K;
  float acc = 0.f;
  for (int k = lane * 2; k + 1 < K; k += 128) {
    float2 av = *(const float2*)(ar + k);
    float2 bv2 = *(const float2*)(br + k);
    acc += av.x * bv2.x + av.y * bv2.y;
  }
#pragma unroll
  for (int off = 32; off; off >>= 1) acc += __shfl_xor(acc, off);
  if (lane == 0) cbuf[wid] = fmaxf(acc + bc[m], 0.f);
}

// ---------------- per-batch-row: q = relu(cbuf@Wq+bq) (LDS) then BAN contraction ------
__global__ void k_fusedq(const float* __restrict__ cbuf, const float* __restrict__ Wqt,
                         const float* __restrict__ bq, const float* __restrict__ vvec,
                         const float* __restrict__ hmat, const float* __restrict__ hbias,
                         float* __restrict__ logits) {
  int b = blockIdx.x, t = threadIdx.x;  // 256 threads
  __shared__ float q[384];
  __shared__ float red[128];
  const float* cr = cbuf + (size_t)b * 128;
  for (int j = t; j < 384; j += 256) {
    const float* wr = Wqt + (size_t)j * 128;
    float acc = bq[j];
    for (int k = 0; k < 128; k += 4) {
      float4 cv = *(const float4*)(cr + k);
      float4 wv = *(const float4*)(wr + k);
      acc += cv.x * wv.x + cv.y * wv.y + cv.z * wv.z + cv.w * wv.w;
    }
    q[j] = fmaxf(acc, 0.f);
  }
  __syncthreads();
  if (t < 128) {
    int c = t;
    float tt[3];
    float part = 0.f;
#pragma unroll
    for (int j = 0; j < 3; j++) {
      int k = c * 3 + j;
      float hs = hmat[k] + hmat[384 + k] + hmat[768 + k] + hmat[1152 + k];
      tt[j] = vvec[k] * q[k];
      part += hs * tt[j];
    }
    red[c] = part;
    // stash t-sum in q[] slot for later (reuse LDS)
    q[c] = tt[0] + tt[1] + tt[2];
  }
  __syncthreads();
  if (t < 64) { red[t] += red[t + 64]; }
  __syncthreads();
  if (t < 32) { red[t] += red[t + 32]; }
  __syncthreads();
  if (t < 16) { red[t] += red[t + 16]; }
  __syncthreads();
  if (t < 8) { red[t] += red[t + 8]; }
  __syncthreads();
  if (t < 4) { red[t] += red[t + 4]; }
  __syncthreads();
  if (t < 2) { red[t] += red[t + 2]; }
  __syncthreads();
  if (t == 0) { red[0] += red[1]; }
  __syncthreads();
  if (t < 128) {
    float attsum = red[0] + (hbias[0] + hbias[1] + hbias[2] + hbias[3]);
    logits[(size_t)b * 128 + t] = attsum * q[t];
  }
}

// batchnorm over batch dim (biased var), one block per channel c
__global__ void k_bn(const float* __restrict__ logits, const float* __restrict__ gamma,
                     const float* __restrict__ beta, float* __restrict__ out, int B) {
  int c = blockIdx.x, b = threadIdx.x;  // B threads
  __shared__ float s1[256], s2[256];
  float v = logits[(size_t)b * 128 + c];
  s1[b] = v; s2[b] = v * v;
  __syncthreads();
  for (int s = B / 2; s > 0; s >>= 1) {
    if (b < s) { s1[b] += s1[b + s]; s2[b] += s2[b + s]; }
    __syncthreads();
  }
  float mu = s1[0] / B;
  float var = s2[0] / B - mu * mu;
  out[(size_t)b * 128 + c] = (v - mu) * rsqrtf(var + 1e-5f) * gamma[c] + beta[c];
}

extern "C" void kernel_launch(void* const* d_in, const int* in_sizes, int n_in,
                              void* d_out, int out_size, void* d_ws, size_t ws_size,
                              hipStream_t stream) {
  const float* cell = (const float*)d_in[0];
  const float* Wd   = (const float*)d_in[1];
  const float* bd   = (const float*)d_in[2];
  const float* W1   = (const float*)d_in[3];
  const float* a1s  = (const float*)d_in[4];
  const float* a1d  = (const float*)d_in[5];
  const float* b1   = (const float*)d_in[6];
  const float* Wl1  = (const float*)d_in[7];
  const float* bl1  = (const float*)d_in[8];
  const float* W2   = (const float*)d_in[9];
  const float* a2s  = (const float*)d_in[10];
  const float* a2d  = (const float*)d_in[11];
  const float* b2   = (const float*)d_in[12];
  const float* Wl2  = (const float*)d_in[13];
  const float* bl2  = (const float*)d_in[14];
  const float* Wfc  = (const float*)d_in[15];
  const float* bfc  = (const float*)d_in[16];
  const float* Whg  = (const float*)d_in[17];
  const float* bhg  = (const float*)d_in[18];
  const float* Wc   = (const float*)d_in[19];
  const float* bc   = (const float*)d_in[20];
  const float* Wv   = (const float*)d_in[21];
  const float* bv   = (const float*)d_in[22];
  const float* Wq   = (const float*)d_in[23];
  const float* bq   = (const float*)d_in[24];
  const float* hmat = (const float*)d_in[25];
  const float* hbias= (const float*)d_in[26];
  const float* gamma= (const float*)d_in[27];
  const float* beta = (const float*)d_in[28];
  const int* trip   = (const int*)d_in[29];
  const int* eidx   = (const int*)d_in[30];

  const int N = in_sizes[29] / 4;     // 20000
  const int E = in_sizes[30] / 2;     // 500000
  const int B = in_sizes[0] / 954;    // 256
  float* out = (float*)d_out;

  // ---------------- workspace layout: bf16 region first (16B aligned) ----------------
  __hip_bfloat16* xb    = (__hip_bfloat16*)d_ws;      // N*128
  __hip_bfloat16* xhb   = xb + (size_t)N * 128;       // N*640  (head-major [H][N][128])
  __hip_bfloat16* goutb = xhb + (size_t)N * 640;      // N*640  (row-major [N][H*128])
  __hip_bfloat16* h1b   = goutb + (size_t)N * 640;    // N*128
  __hip_bfloat16* h2b   = h1b + (size_t)N * 128;      // N*128
  __hip_bfloat16* W1t   = h2b + (size_t)N * 128;      // 512*128
  __hip_bfloat16* Wl1t  = W1t + 512 * 128;            // 128*512
  __hip_bfloat16* W2t   = Wl1t + 128 * 512;           // 640*128
  __hip_bfloat16* Wl2t  = W2t + 640 * 128;            // 128*640
  // f32 region: per-layer es/ed (contiguous 18N for one-shot zeroing)
  float* es1    = (float*)(Wl2t + 128 * 640);  // 4N
  float* ed1    = es1 + (size_t)4 * N;         // 4N
  float* es2    = ed1 + (size_t)4 * N;         // 5N
  float* ed2    = es2 + (size_t)5 * N;         // 5N
  float* colsum = ed2 + (size_t)5 * N;         // 128
  float* cbuf   = colsum + 128;                // B*128
  float* vvec   = cbuf + (size_t)B * 128;      // 384
  float* logits = vvec + 384;                  // B*128
  float* Wct    = logits + (size_t)B * 128;    // 128*954
  float* Wqt    = Wct + 128 * 954;             // 384*128
  // int region
  int* rowptr   = (int*)(Wqt + 384 * 128);     // N+1
  int* degb     = rowptr + (N + 1);            // N
  int* cursor   = degb + N;                    // N (contiguous after degb)
  int* adj      = cursor + N;                  // E

  const int* src0 = eidx;
  const int* dst0 = eidx + E;

  // weight transposes + zeroing of colsum/degb/cursor/es/ed in one launch
  {
    int tot = 128*512 + 512*128 + 128*640 + 640*128 + 954*128 + 128*384
              + 128 + 2 * N + 18 * N;
    k_prep<<<CDIV(tot, 256), 256, 0, stream>>>(W1, W1t, Wl1, Wl1t, W2, W2t, Wl2, Wl2t,
                                               Wc, Wct, Wq, Wqt, colsum, degb, es1, N);
  }

  // degree count + drug linear in one dispatch
  k_degdrug<<<CDIV(E + N * 128, 256), 256, 0, stream>>>(src0, dst0, degb, E,
                                                        trip, Wd, bd, xb, N);
  k_scan<<<1, 1024, 0, stream>>>(degb, rowptr, N);
  k_fill_adj<<<CDIV(E, 256), 256, 0, stream>>>(src0, dst0, rowptr, cursor, adj, E);

  // ---------------- GAT1 (H=4) ----------------
  {
    dim3 g(512 / 64, CDIV(N, 64));
    k_gemm_mfma<false, false, true><<<g, 256, 0, stream>>>(
        xb, W1t, nullptr, xhb, nullptr, a1s, a1d, es1, ed1, N, 128, 512);
  }
  {
    dim3 g(CDIV(N, 4), 4);
    k_gat_gather<<<g, 256, 0, stream>>>(rowptr, adj, es1, ed1, xhb, b1, goutb, N, 4);
  }
  {
    dim3 g(128 / 64, CDIV(N, 64));
    k_gemm_mfma<true, true, false><<<g, 256, 0, stream>>>(
        goutb, Wl1t, bl1, h1b, colsum, nullptr, nullptr, nullptr, nullptr, N, 512, 128);
  }

  // ---------------- GAT2 (H=5) ----------------
  {
    dim3 g(640 / 64, CDIV(N, 64));
    k_gemm_mfma<false, false, true><<<g, 256, 0, stream>>>(
        h1b, W2t, nullptr, xhb, nullptr, a2s, a2d, es2, ed2, N, 128, 640);
  }
  {
    dim3 g(CDIV(N, 4), 5);
    k_gat_gather<<<g, 256, 0, stream>>>(rowptr, adj, es2, ed2, xhb, b2, goutb, N, 5);
  }
  {
    dim3 g(128 / 64, CDIV(N, 64));
    k_gemm_mfma<true, true, false><<<g, 256, 0, stream>>>(
        goutb, Wl2t, bl2, h2b, colsum, nullptr, nullptr, nullptr, nullptr, N, 640, 128);
  }

  // ---------------- head + BAN + BN (fused tail) ----------------
  k_headdot<<<1 + CDIV(B * 128, 4), 256, 0, stream>>>(
      colsum, Wfc, bfc, Whg, bhg, Wv, bv, vvec, 1.0f / N,
      cell, Wct, bc, cbuf, B, 954, 128);
  k_fusedq<<<B, 256, 0, stream>>>(cbuf, Wqt, bq, vvec, hmat, hbias, logits);
  k_bn<<<128, B, 0, stream>>>(logits, gamma, beta, out, B);
}